// Round 14
// baseline (146.877 us; speedup 1.0000x reference)
//
#include <hip/hip_runtime.h>
#include <stdint.h>

#define V3 110592        // 48*48*48
#define PLANE 2304       // 48*48
#define NO 64

typedef unsigned short ushort_t;
typedef __attribute__((ext_vector_type(8))) short short8v;
typedef __attribute__((ext_vector_type(4))) float float4v;

__device__ __forceinline__ uint32_t f2bf1(float f) {
  uint32_t u = __float_as_uint(f);
  u += 0x7FFFu + ((u >> 16) & 1u);   // RNE
  return u >> 16;
}
__device__ __forceinline__ uint32_t pack2(float a, float b) {
  return f2bf1(a) | (f2bf1(b) << 16);
}

// Afr[g][m][8] bf16, kk = dzi*192 + i*6 + qi, g=kk/8.
__device__ __forceinline__ void prep_body(const float* __restrict__ w,
                                          ushort_t* __restrict__ Afr, int idx) {
  int r = idx & 7, m = (idx >> 3) & 63, g = idx >> 9;
  int kk = g * 8 + r;
  int dzi = kk / 192, k2 = kk % 192;
  int i = k2 / 6, qi = k2 % 6;
  const int Q[6] = {0, 1, 2, 4, 5, 8};
  const int pidx[13] = {0, 1, 2, 3, 4, 5, 6, 0, 7, 8, 0, 0, 9};  // r2 -> shell
  int dz = dzi - 2;
  int p = pidx[Q[qi] + dz * dz];
  Afr[idx] = (ushort_t)f2bf1(0.28209479177387814f * w[(m * 32 + i) * 10 + p]);
}

// ---------- pass 1: per-plane 2D class sums (R4-verified body) ----------
// R10 (kept): writer->reader XCD alignment.
__global__ __launch_bounds__(256, 4) void bq_kernel(const float* __restrict__ x,
                                                    ushort_t* __restrict__ Bq,
                                                    const float* __restrict__ w,
                                                    ushort_t* __restrict__ Afr,
                                                    int zbase) {
  const int tid = threadIdx.x;
  const int b = blockIdx.x;
  if (zbase == 0 && b < 240) prep_body(w, Afr, b * 256 + tid);

  const int q = b & 7;
  const int dg = q >> 1, half = q & 1;
  const int s = b >> 3;
  const int dl = s % 12;
  const int ig = (s / 12) & 7;
  const int z = zbase + s / 96;
  const int d = dg * 12 + dl;

  const int lane = tid & 63;
  const int strip = tid >> 6;                    // 0..3
  const float* xb = x + (size_t)z * 32 * V3;
  ushort_t* Bqb = Bq + (size_t)z * ((size_t)1152 * PLANE * 8);

  const int h0 = (half * 4 + strip) * 6;         // 6-row strip base
  const int gw = lane - 2;
  const bool okw = (gw >= 0 && gw < 48);
  const int sl1 = lane > 0 ? lane - 1 : 0;
  const int sl2 = lane > 1 ? lane - 2 : 0;
  const int sr1 = lane < 63 ? lane + 1 : 63;
  const int sr2 = lane < 62 ? lane + 2 : 63;
  const bool okst = (lane >= 2 && lane <= 49);

  const float* px[4];
#pragma unroll
  for (int ii = 0; ii < 4; ++ii)
    px[ii] = xb + ((size_t)(ig * 4 + ii) * 48 + d) * PLANE + gw;

  // phase 1: all loads in flight
  float v[10][4];
#pragma unroll
  for (int r = 0; r < 10; ++r) {
    const int gh = h0 - 2 + r;
    const bool okv = okw && (gh >= 0) && (gh < 48);
#pragma unroll
    for (int ii = 0; ii < 4; ++ii)
      v[r][ii] = okv ? px[ii][gh * 48] : 0.f;
  }

  // phase 2: shfl class-sums
  float s1[4][5], s4[4][5];
#pragma unroll
  for (int r = 0; r < 10; ++r) {
    const int slot = r % 5;
#pragma unroll
    for (int ii = 0; ii < 4; ++ii) {
      float val = v[r][ii];
      float vl1 = __shfl(val, sl1);
      float vr1 = __shfl(val, sr1);
      float vl2 = __shfl(val, sl2);
      float vr2 = __shfl(val, sr2);
      s1[ii][slot] = vl1 + vr1;                  // dx^2 = 1
      s4[ii][slot] = vl2 + vr2;                  // dx^2 = 4
    }
    if (r >= 4) {
      const int j0 = (r - 4) % 5, j1 = (r - 3) % 5, j2 = (r - 2) % 5,
                j3 = (r - 1) % 5, j4 = r % 5;
      uint32_t dw[12];
#pragma unroll
      for (int ii = 0; ii < 4; ++ii) {
        float B0 = v[r - 2][ii];
        float B1 = s1[ii][j2] + v[r - 3][ii] + v[r - 1][ii];
        float B2 = s1[ii][j1] + s1[ii][j3];
        float B3 = s4[ii][j2] + v[r - 4][ii] + v[r][ii];
        float B4 = s4[ii][j1] + s4[ii][j3] + s1[ii][j0] + s1[ii][j4];
        float B5 = s4[ii][j0] + s4[ii][j4];
        dw[ii * 3 + 0] = pack2(B0, B1);
        dw[ii * 3 + 1] = pack2(B2, B3);
        dw[ii * 3 + 2] = pack2(B4, B5);
      }
      if (okst) {
        const int n = (h0 + r - 4) * 48 + gw;
        const size_t gb = (size_t)(d * 24 + ig * 3);
        uint4 c0 = {dw[0], dw[1], dw[2], dw[3]};
        uint4 c1 = {dw[4], dw[5], dw[6], dw[7]};
        uint4 c2 = {dw[8], dw[9], dw[10], dw[11]};
        *(uint4*)(Bqb + ((gb + 0) * PLANE + n) * 8) = c0;
        *(uint4*)(Bqb + ((gb + 1) * PLANE + n) * 8) = c1;
        *(uint4*)(Bqb + ((gb + 2) * PLANE + n) * 8) = c2;
      }
    }
  }
}

// ---------- pass 2: GEMM, LDS-staged A + 3-deep B FIFO + no-drain barriers ----------
// R13 (verified, 51.8->44.7 us): A staged per-dzi into double-buffered LDS.
// R14: two residual stalls removed.
//  (1) __syncthreads drained vmcnt(0), killing B-prefetch across dzi
//      boundaries. Replaced by counted `s_waitcnt vmcnt(4)` + raw s_barrier:
//      queue at barrier = [6 stage loads (oldest), 4 B loads (newest)];
//      vmcnt(4) proves stage retired (in-order count) while the 2 in-flight
//      B sets survive the barrier (m218/T4 pattern).
//  (2) B depth 1 -> 3: rolling Bv[3][2] FIFO across the whole T-trip walk
//      (ks%3 static in the unrolled loop, rule #20), ~310 cy coverage.
__global__ __launch_bounds__(256, 3) void gemm_kernel(const ushort_t* __restrict__ Bq,
                                                      const ushort_t* __restrict__ Afr,
                                                      const float* __restrict__ bias,
                                                      float* __restrict__ out) {
  const int tid = threadIdx.x;
  const int lane = tid & 63, wi = tid >> 6;
  const int quad = lane >> 4, m15 = lane & 15;
  const int b = blockIdx.x;                      // 0..863 flat
  const int p = b & 7;                           // XCD partition
  const int s = b >> 3;                          // 0..107
  const int dl = s / 9;                          // 0..11
  const int nbl = s - dl * 9;                    // 0..8
  const int d = (p >> 1) * 12 + dl;              // output plane
  const int n0 = ((p & 1) * 9 + nbl) * 128 + wi * 32;
  const ushort_t* Bqb = Bq + (size_t)blockIdx.z * ((size_t)1152 * PLANE * 8);
  float* outb = out + (size_t)blockIdx.z * (size_t)NO * V3;

  const int lo = (d < 2) ? (2 - d) : 0;
  const int hi = (d > 45) ? (49 - d) : 4;

  __shared__ ushort_t sA[2][12288];              // 2 x 24 KB

  // stage dzi-slice (24 KB linear): LDS dest wave-uniform (+lane*16 by HW)
#define STAGE(DZI, BUF)                                                        \
  {                                                                            \
    const ushort_t* src_ = Afr + (size_t)(DZI) * 12288 + tid * 8;              \
    ushort_t* dst_ = &sA[BUF][(tid >> 6) * 512];                               \
    _Pragma("unroll") for (int r_ = 0; r_ < 6; ++r_)                           \
        __builtin_amdgcn_global_load_lds(                                      \
            (const __attribute__((address_space(1))) void*)(src_ + r_ * 2048), \
            (__attribute__((address_space(3))) void*)(dst_ + r_ * 2048),       \
            16, 0, 0);                                                         \
  }
  // no-drain barrier: stage loads are the oldest entries; vmcnt(4) retires
  // them while leaving the 2 newest B sets (4 loads) in flight.
#define NODRAIN_BARRIER                                                        \
  {                                                                            \
    asm volatile("s_waitcnt vmcnt(4)" ::: "memory");                           \
    __builtin_amdgcn_sched_barrier(0);                                         \
    __builtin_amdgcn_s_barrier();                                              \
  }

  const ushort_t* bp = Bqb + ((size_t)((d - 2) * 24 + 6 * lo * 4 + quad) * PLANE + n0 + m15) * 8;
  const int bstep = 4 * PLANE * 8;

  float4v acc[4][2];
#pragma unroll
  for (int mt = 0; mt < 4; ++mt)
#pragma unroll
    for (int nt = 0; nt < 2; ++nt) acc[mt][nt] = (float4v){0.f, 0.f, 0.f, 0.f};

  short8v Bv[3][2];                              // rolling FIFO, static idx

  STAGE(lo, 0);
  // B prologue: trips 0 and 1 (queue: 6 stage + 4 B)
#pragma unroll
  for (int nt = 0; nt < 2; ++nt) Bv[0][nt] = *(const short8v*)(bp + nt * 128);
  bp += bstep;
#pragma unroll
  for (int nt = 0; nt < 2; ++nt) Bv[1][nt] = *(const short8v*)(bp + nt * 128);
  bp += bstep;
  NODRAIN_BARRIER;

  int buf = 0;
  for (int dzi = lo; dzi <= hi; ++dzi) {
    if (dzi < hi) STAGE(dzi + 1, buf ^ 1);       // oldest in queue this dzi
    const ushort_t* sAb = &sA[buf][(size_t)quad * 512 + m15 * 8];
#pragma unroll
    for (int ks = 0; ks < 6; ++ks) {
      // issue B for trip t+2 (skip only for the final two trips overall)
      if (!(dzi == hi && ks >= 4)) {
#pragma unroll
        for (int nt = 0; nt < 2; ++nt)
          Bv[(ks + 2) % 3][nt] = *(const short8v*)(bp + nt * 128);
        bp += bstep;
      }
      short8v a0 = *(const short8v*)(sAb + ks * 2048 + 0 * 128);
      short8v a1 = *(const short8v*)(sAb + ks * 2048 + 1 * 128);
      short8v a2 = *(const short8v*)(sAb + ks * 2048 + 2 * 128);
      short8v a3 = *(const short8v*)(sAb + ks * 2048 + 3 * 128);
      __builtin_amdgcn_s_setprio(1);
#pragma unroll
      for (int nt = 0; nt < 2; ++nt) {
        acc[0][nt] = __builtin_amdgcn_mfma_f32_16x16x32_bf16(a0, Bv[ks % 3][nt], acc[0][nt], 0, 0, 0);
        acc[1][nt] = __builtin_amdgcn_mfma_f32_16x16x32_bf16(a1, Bv[ks % 3][nt], acc[1][nt], 0, 0, 0);
        acc[2][nt] = __builtin_amdgcn_mfma_f32_16x16x32_bf16(a2, Bv[ks % 3][nt], acc[2][nt], 0, 0, 0);
        acc[3][nt] = __builtin_amdgcn_mfma_f32_16x16x32_bf16(a3, Bv[ks % 3][nt], acc[3][nt], 0, 0, 0);
      }
      __builtin_amdgcn_s_setprio(0);
    }
    if (dzi < hi) NODRAIN_BARRIER;               // buf^1 staged; B FIFO alive
    buf ^= 1;
  }
#undef STAGE
#undef NODRAIN_BARRIER

  // C/D: col(n) = lane&15, row(m) = quad*4 + reg; nontemporal out stores
  const int vb = d * PLANE + n0 + m15;
#pragma unroll
  for (int mt = 0; mt < 4; ++mt) {
#pragma unroll
    for (int r = 0; r < 4; ++r) {
      int m = mt * 16 + quad * 4 + r;
      float bv = bias[m];
      float* op = outb + (size_t)m * V3 + vb;
#pragma unroll
      for (int nt = 0; nt < 2; ++nt)
        __builtin_nontemporal_store(acc[mt][nt][r] + bv, op + nt * 16);
    }
  }
}

extern "C" void kernel_launch(void* const* d_in, const int* in_sizes, int n_in,
                              void* d_out, int out_size, void* d_ws, size_t ws_size,
                              hipStream_t stream) {
  const float* x    = (const float*)d_in[0];   // [2,32,1,48,48,48]
  const float* w    = (const float*)d_in[1];   // [64,32,1,1,1,10]
  const float* bias = (const float*)d_in[2];   // [64]
  float* out = (float*)d_out;                  // [2,64,1,48,48,48]

  ushort_t* Afr = (ushort_t*)d_ws;                         // 122880 B
  ushort_t* Bq  = (ushort_t*)((char*)d_ws + 131072);
  const size_t SB = (size_t)1152 * PLANE * 8 * 2;          // 42.5 MB per batch
  const bool both = (ws_size >= 131072 + 2 * SB);

  if (both) {
    bq_kernel<<<dim3(1536), 256, 0, stream>>>(x, Bq, w, Afr, 0);
    gemm_kernel<<<dim3(864, 1, 2), 256, 0, stream>>>(Bq, Afr, bias, out);
  } else {
    for (int b = 0; b < 2; ++b) {
      bq_kernel<<<dim3(768), 256, 0, stream>>>(x + (size_t)b * 32 * V3, Bq, w, Afr, 0);
      gemm_kernel<<<dim3(864, 1, 1), 256, 0, stream>>>(Bq, Afr, bias,
                                                       out + (size_t)b * NO * V3);
    }
  }
}

// Round 15
// 144.817 us; speedup vs baseline: 1.0142x; 1.0142x over previous
//
#include <hip/hip_runtime.h>
#include <stdint.h>

#define V3 110592        // 48*48*48
#define PLANE 2304       // 48*48
#define NO 64

typedef unsigned short ushort_t;
typedef __attribute__((ext_vector_type(8))) short short8v;
typedef __attribute__((ext_vector_type(4))) float float4v;

__device__ __forceinline__ uint32_t f2bf1(float f) {
  uint32_t u = __float_as_uint(f);
  u += 0x7FFFu + ((u >> 16) & 1u);   // RNE
  return u >> 16;
}
__device__ __forceinline__ uint32_t pack2(float a, float b) {
  return f2bf1(a) | (f2bf1(b) << 16);
}

// Afr[g][m][8] bf16, kk = dzi*192 + i*6 + qi, g=kk/8.
__device__ __forceinline__ void prep_body(const float* __restrict__ w,
                                          ushort_t* __restrict__ Afr, int idx) {
  int r = idx & 7, m = (idx >> 3) & 63, g = idx >> 9;
  int kk = g * 8 + r;
  int dzi = kk / 192, k2 = kk % 192;
  int i = k2 / 6, qi = k2 % 6;
  const int Q[6] = {0, 1, 2, 4, 5, 8};
  const int pidx[13] = {0, 1, 2, 3, 4, 5, 6, 0, 7, 8, 0, 0, 9};  // r2 -> shell
  int dz = dzi - 2;
  int p = pidx[Q[qi] + dz * dz];
  Afr[idx] = (ushort_t)f2bf1(0.28209479177387814f * w[(m * 32 + i) * 10 + p]);
}

// ---------- pass 1: per-plane 2D class sums (R4-verified body) ----------
// R10 (kept): writer->reader XCD alignment — (d, half) producer runs on the
// XCD whose gemm partition reads that half-plane.
__global__ __launch_bounds__(256, 4) void bq_kernel(const float* __restrict__ x,
                                                    ushort_t* __restrict__ Bq,
                                                    const float* __restrict__ w,
                                                    ushort_t* __restrict__ Afr,
                                                    int zbase) {
  const int tid = threadIdx.x;
  const int b = blockIdx.x;
  if (zbase == 0 && b < 240) prep_body(w, Afr, b * 256 + tid);

  const int q = b & 7;
  const int dg = q >> 1, half = q & 1;
  const int s = b >> 3;
  const int dl = s % 12;
  const int ig = (s / 12) & 7;
  const int z = zbase + s / 96;
  const int d = dg * 12 + dl;

  const int lane = tid & 63;
  const int strip = tid >> 6;                    // 0..3
  const float* xb = x + (size_t)z * 32 * V3;
  ushort_t* Bqb = Bq + (size_t)z * ((size_t)1152 * PLANE * 8);

  const int h0 = (half * 4 + strip) * 6;         // 6-row strip base
  const int gw = lane - 2;
  const bool okw = (gw >= 0 && gw < 48);
  const int sl1 = lane > 0 ? lane - 1 : 0;
  const int sl2 = lane > 1 ? lane - 2 : 0;
  const int sr1 = lane < 63 ? lane + 1 : 63;
  const int sr2 = lane < 62 ? lane + 2 : 63;
  const bool okst = (lane >= 2 && lane <= 49);

  const float* px[4];
#pragma unroll
  for (int ii = 0; ii < 4; ++ii)
    px[ii] = xb + ((size_t)(ig * 4 + ii) * 48 + d) * PLANE + gw;

  // phase 1: all loads in flight
  float v[10][4];
#pragma unroll
  for (int r = 0; r < 10; ++r) {
    const int gh = h0 - 2 + r;
    const bool okv = okw && (gh >= 0) && (gh < 48);
#pragma unroll
    for (int ii = 0; ii < 4; ++ii)
      v[r][ii] = okv ? px[ii][gh * 48] : 0.f;
  }

  // phase 2: shfl class-sums
  float s1[4][5], s4[4][5];
#pragma unroll
  for (int r = 0; r < 10; ++r) {
    const int slot = r % 5;
#pragma unroll
    for (int ii = 0; ii < 4; ++ii) {
      float val = v[r][ii];
      float vl1 = __shfl(val, sl1);
      float vr1 = __shfl(val, sr1);
      float vl2 = __shfl(val, sl2);
      float vr2 = __shfl(val, sr2);
      s1[ii][slot] = vl1 + vr1;                  // dx^2 = 1
      s4[ii][slot] = vl2 + vr2;                  // dx^2 = 4
    }
    if (r >= 4) {
      const int j0 = (r - 4) % 5, j1 = (r - 3) % 5, j2 = (r - 2) % 5,
                j3 = (r - 1) % 5, j4 = r % 5;
      uint32_t dw[12];
#pragma unroll
      for (int ii = 0; ii < 4; ++ii) {
        float B0 = v[r - 2][ii];
        float B1 = s1[ii][j2] + v[r - 3][ii] + v[r - 1][ii];
        float B2 = s1[ii][j1] + s1[ii][j3];
        float B3 = s4[ii][j2] + v[r - 4][ii] + v[r][ii];
        float B4 = s4[ii][j1] + s4[ii][j3] + s1[ii][j0] + s1[ii][j4];
        float B5 = s4[ii][j0] + s4[ii][j4];
        dw[ii * 3 + 0] = pack2(B0, B1);
        dw[ii * 3 + 1] = pack2(B2, B3);
        dw[ii * 3 + 2] = pack2(B4, B5);
      }
      if (okst) {
        const int n = (h0 + r - 4) * 48 + gw;
        const size_t gb = (size_t)(d * 24 + ig * 3);
        uint4 c0 = {dw[0], dw[1], dw[2], dw[3]};
        uint4 c1 = {dw[4], dw[5], dw[6], dw[7]};
        uint4 c2 = {dw[8], dw[9], dw[10], dw[11]};
        *(uint4*)(Bqb + ((gb + 0) * PLANE + n) * 8) = c0;
        *(uint4*)(Bqb + ((gb + 1) * PLANE + n) * 8) = c1;
        *(uint4*)(Bqb + ((gb + 2) * PLANE + n) * 8) = c2;
      }
    }
  }
}

// ---------- pass 2: GEMM with LDS-staged A (R13-verified, best: 44.7 us) ----------
// out[m][d,n] = sum_kk Afr[kk][m] * Bq[(d-2)*24 + kk/8][n][kk%8] + bias[m]
// R15 = exact R13 revert. R14's two deltas (vmcnt(4) no-drain barrier,
// 3-deep B FIFO) both regressed (44.7 -> 48.3 us): the counted-vmcnt barrier
// retires late-issued B loads too (stalls on unneeded B), and the FIFO's 48
// live B-VGPRs lengthened the loop. R13's plain __syncthreads costs ~nothing
// because the stage has ~940 cy of MFMA to complete under. Keep: A staged
// per-dzi into double-buffered LDS via global_load_lds (the R13 win: takes A
// off the per-trip global chain; per-trip = 4 ds_read + 2 B loads + 8 MFMA;
// B ping-pong needs only 16 VGPR so the allocator has nothing to collapse).
__global__ __launch_bounds__(256, 3) void gemm_kernel(const ushort_t* __restrict__ Bq,
                                                      const ushort_t* __restrict__ Afr,
                                                      const float* __restrict__ bias,
                                                      float* __restrict__ out) {
  const int tid = threadIdx.x;
  const int lane = tid & 63, wi = tid >> 6;
  const int quad = lane >> 4, m15 = lane & 15;
  const int b = blockIdx.x;                      // 0..863 flat
  const int p = b & 7;                           // XCD partition
  const int s = b >> 3;                          // 0..107
  const int dl = s / 9;                          // 0..11
  const int nbl = s - dl * 9;                    // 0..8
  const int d = (p >> 1) * 12 + dl;              // output plane
  const int n0 = ((p & 1) * 9 + nbl) * 128 + wi * 32;
  const ushort_t* Bqb = Bq + (size_t)blockIdx.z * ((size_t)1152 * PLANE * 8);
  float* outb = out + (size_t)blockIdx.z * (size_t)NO * V3;

  const int lo = (d < 2) ? (2 - d) : 0;
  const int hi = (d > 45) ? (49 - d) : 4;

  __shared__ ushort_t sA[2][12288];              // 2 x 24 KB

  // stage dzi-slice (24 KB, linear copy): round r moves 4 KB; LDS dest is
  // wave-uniform (wave base + r*4096), HW adds lane*16; src is per-lane.
#define STAGE(DZI, BUF)                                                        \
  {                                                                            \
    const ushort_t* src_ = Afr + (size_t)(DZI) * 12288 + tid * 8;              \
    ushort_t* dst_ = &sA[BUF][(tid >> 6) * 512];                               \
    _Pragma("unroll") for (int r_ = 0; r_ < 6; ++r_)                           \
        __builtin_amdgcn_global_load_lds(                                      \
            (const __attribute__((address_space(1))) void*)(src_ + r_ * 2048), \
            (__attribute__((address_space(3))) void*)(dst_ + r_ * 2048),       \
            16, 0, 0);                                                         \
  }

  const ushort_t* bp = Bqb + ((size_t)((d - 2) * 24 + 6 * lo * 4 + quad) * PLANE + n0 + m15) * 8;
  const int bstep = 4 * PLANE * 8;

  float4v acc[4][2];
#pragma unroll
  for (int mt = 0; mt < 4; ++mt)
#pragma unroll
    for (int nt = 0; nt < 2; ++nt) acc[mt][nt] = (float4v){0.f, 0.f, 0.f, 0.f};

  short8v Bc[2], Bn[2];

  STAGE(lo, 0);
  // initial B (overlaps the stage; drained by the barrier's vmcnt(0))
#pragma unroll
  for (int nt = 0; nt < 2; ++nt) Bc[nt] = *(const short8v*)(bp + nt * 128);
  bp += bstep;
  __syncthreads();

  int buf = 0;
  for (int dzi = lo; dzi <= hi; ++dzi) {
    if (dzi < hi) STAGE(dzi + 1, buf ^ 1);
    const ushort_t* sAb = &sA[buf][(size_t)quad * 512 + m15 * 8];
#pragma unroll
    for (int ks = 0; ks < 6; ++ks) {
      const bool last = (dzi == hi) && (ks == 5);
      if (!last) {
#pragma unroll
        for (int nt = 0; nt < 2; ++nt) Bn[nt] = *(const short8v*)(bp + nt * 128);
        bp += bstep;
      }
      short8v a0 = *(const short8v*)(sAb + ks * 2048 + 0 * 128);
      short8v a1 = *(const short8v*)(sAb + ks * 2048 + 1 * 128);
      short8v a2 = *(const short8v*)(sAb + ks * 2048 + 2 * 128);
      short8v a3 = *(const short8v*)(sAb + ks * 2048 + 3 * 128);
      __builtin_amdgcn_s_setprio(1);
#pragma unroll
      for (int nt = 0; nt < 2; ++nt) {
        acc[0][nt] = __builtin_amdgcn_mfma_f32_16x16x32_bf16(a0, Bc[nt], acc[0][nt], 0, 0, 0);
        acc[1][nt] = __builtin_amdgcn_mfma_f32_16x16x32_bf16(a1, Bc[nt], acc[1][nt], 0, 0, 0);
        acc[2][nt] = __builtin_amdgcn_mfma_f32_16x16x32_bf16(a2, Bc[nt], acc[2][nt], 0, 0, 0);
        acc[3][nt] = __builtin_amdgcn_mfma_f32_16x16x32_bf16(a3, Bc[nt], acc[3][nt], 0, 0, 0);
      }
      __builtin_amdgcn_s_setprio(0);
      Bc[0] = Bn[0]; Bc[1] = Bn[1];
    }
    __syncthreads();                             // buf^1 staged; buf free
    buf ^= 1;
  }
#undef STAGE

  // C/D: col(n) = lane&15, row(m) = quad*4 + reg; nontemporal out stores
  const int vb = d * PLANE + n0 + m15;
#pragma unroll
  for (int mt = 0; mt < 4; ++mt) {
#pragma unroll
    for (int r = 0; r < 4; ++r) {
      int m = mt * 16 + quad * 4 + r;
      float bv = bias[m];
      float* op = outb + (size_t)m * V3 + vb;
#pragma unroll
      for (int nt = 0; nt < 2; ++nt)
        __builtin_nontemporal_store(acc[mt][nt][r] + bv, op + nt * 16);
    }
  }
}

extern "C" void kernel_launch(void* const* d_in, const int* in_sizes, int n_in,
                              void* d_out, int out_size, void* d_ws, size_t ws_size,
                              hipStream_t stream) {
  const float* x    = (const float*)d_in[0];   // [2,32,1,48,48,48]
  const float* w    = (const float*)d_in[1];   // [64,32,1,1,1,10]
  const float* bias = (const float*)d_in[2];   // [64]
  float* out = (float*)d_out;                  // [2,64,1,48,48,48]

  ushort_t* Afr = (ushort_t*)d_ws;                         // 122880 B
  ushort_t* Bq  = (ushort_t*)((char*)d_ws + 131072);
  const size_t SB = (size_t)1152 * PLANE * 8 * 2;          // 42.5 MB per batch
  const bool both = (ws_size >= 131072 + 2 * SB);

  if (both) {
    bq_kernel<<<dim3(1536), 256, 0, stream>>>(x, Bq, w, Afr, 0);
    gemm_kernel<<<dim3(864, 1, 2), 256, 0, stream>>>(Bq, Afr, bias, out);
  } else {
    for (int b = 0; b < 2; ++b) {
      bq_kernel<<<dim3(768), 256, 0, stream>>>(x + (size_t)b * 32 * V3, Bq, w, Afr, 0);
      gemm_kernel<<<dim3(864, 1, 1), 256, 0, stream>>>(Bq, Afr, bias,
                                                       out + (size_t)b * NO * V3);
    }
  }
}